// Round 7
// baseline (182.809 us; speedup 1.0000x reference)
//
#include <hip/hip_runtime.h>
#include <hip/hip_bf16.h>

__device__ __forceinline__ float bf2f(unsigned short u) {
    union { unsigned int i; float f; } v; v.i = ((unsigned int)u) << 16; return v.f;
}
__device__ __forceinline__ unsigned short f2bf(float f) {
    __hip_bfloat16 h = __float2bfloat16(f);
    return *reinterpret_cast<unsigned short*>(&h);
}

// ws: Q fp32 [b][g][pix][ci] (4 MB) | K bf16 (2 MB) | V bf16 (2 MB)

// ---------------------------------------------------------------------------
// conv: three 1x1 convs, fp32 in/weights, fp32 accum.  (unchanged from R6)
// Register-tiled GEMM: block = 128 out-ch x 64 px, thread = 8 ch x 4 px.
// Q -> fp32, K/V -> bf16, layout [b][g][pix][ci]. grid (128 px-tiles, 3).
// ---------------------------------------------------------------------------
__global__ __launch_bounds__(256) void conv_kernel(
    const float* __restrict__ fm,
    const float* __restrict__ wq, const float* __restrict__ wk,
    const float* __restrict__ wv,
    float* __restrict__ Qout,
    unsigned short* __restrict__ K0,
    unsigned short* __restrict__ V0)
{
    const int sel = blockIdx.y;
    const float* W = (sel == 0) ? wq : ((sel == 1) ? wk : wv);
    const int c0 = (sel == 0) ? 128 : 0;

    __shared__ float w_s[64 * 132];
    __shared__ float x_s[64 * 68];

    const int tid = threadIdx.x;
    const int P0  = blockIdx.x * 64;
    const int b   = P0 >> 12;
    const int hw0 = P0 & 4095;

    float acc[8][4];
    #pragma unroll
    for (int i = 0; i < 8; ++i)
        #pragma unroll
        for (int j = 0; j < 4; ++j) acc[i][j] = 0.f;

    const int ocb = (tid >> 4) * 8;
    const int pxb = (tid & 15) * 4;

    for (int kh = 0; kh < 128; kh += 64) {
        {
            const int o    = tid >> 1;
            const int koff = (tid & 1) * 32;
            #pragma unroll
            for (int i = 0; i < 8; ++i) {
                float4 v = *(const float4*)(W + o * 128 + kh + koff + i * 4);
                w_s[(koff + i * 4 + 0) * 132 + o] = v.x;
                w_s[(koff + i * 4 + 1) * 132 + o] = v.y;
                w_s[(koff + i * 4 + 2) * 132 + o] = v.z;
                w_s[(koff + i * 4 + 3) * 132 + o] = v.w;
            }
        }
        {
            const int c  = tid >> 2;
            const int pc = (tid & 3) * 16;
            const float* src = fm + (((size_t)(b * 256 + c0 + kh + c)) << 12) + hw0 + pc;
            #pragma unroll
            for (int i = 0; i < 4; ++i)
                *(float4*)(&x_s[c * 68 + pc + i * 4]) = *(const float4*)(src + i * 4);
        }
        __syncthreads();
        #pragma unroll 8
        for (int k = 0; k < 64; ++k) {
            const float* kw = &w_s[k * 132 + ocb];
            float4 wa = *(const float4*)kw;
            float4 wb = *(const float4*)(kw + 4);
            float4 xv = *(const float4*)(&x_s[k * 68 + pxb]);
            const float wf[8] = {wa.x, wa.y, wa.z, wa.w, wb.x, wb.y, wb.z, wb.w};
            const float xf[4] = {xv.x, xv.y, xv.z, xv.w};
            #pragma unroll
            for (int i = 0; i < 8; ++i)
                #pragma unroll
                for (int j = 0; j < 4; ++j) acc[i][j] += wf[i] * xf[j];
        }
        __syncthreads();
    }

    const int g   = ocb >> 4;
    const int lci = ocb & 8;
    #pragma unroll
    for (int pj = 0; pj < 4; ++pj) {
        const int hw = hw0 + pxb + pj;
        const size_t base = ((((size_t)(b * 8 + g)) << 12) + hw) * 16 + lci;
        if (sel == 0) {
            *(float4*)(Qout + base)     = make_float4(acc[0][pj], acc[1][pj], acc[2][pj], acc[3][pj]);
            *(float4*)(Qout + base + 4) = make_float4(acc[4][pj], acc[5][pj], acc[6][pj], acc[7][pj]);
        } else {
            unsigned short tmp[8];
            #pragma unroll
            for (int i = 0; i < 8; ++i) tmp[i] = f2bf(acc[i][pj]);
            unsigned short* dst = ((sel == 1) ? K0 : V0) + base;
            *(uint4*)dst = *(const uint4*)tmp;
        }
    }
}

// ---------------------------------------------------------------------------
// attn: 4 lanes per (b,g,h,w), each owning 4 channels; quad shfl_xor reduce.
// part 0 = main 7x7 (rel bias), 1 = refine row, 2 = refine col; each part
// atomicAdds into the zeroed fp32 output.
// block 256 = 64 px x 4 splits; grid (64 rows, 8 groups, 6 = b*3+part).
// ---------------------------------------------------------------------------
__device__ __forceinline__ float quadsum(float v) {
    v += __shfl_xor(v, 1);
    v += __shfl_xor(v, 2);
    return v;
}
__device__ __forceinline__ float dot4(const float4& q, uint2 k) {
    const unsigned short* u = (const unsigned short*)&k;
    return q.x * bf2f(u[0]) + q.y * bf2f(u[1]) + q.z * bf2f(u[2]) + q.w * bf2f(u[3]);
}

__global__ __launch_bounds__(256) void attn_kernel(
    const float* __restrict__ Q,
    const unsigned short* __restrict__ K0,
    const unsigned short* __restrict__ V0,
    const float* __restrict__ rel_h,
    const float* __restrict__ rel_w,
    float* __restrict__ out)
{
    const int tid  = threadIdx.x;
    const int s    = tid & 3;        // channel split: owns ch s*4 .. s*4+3
    const int w    = tid >> 2;       // 0..63
    const int h    = blockIdx.x;
    const int g    = blockIdx.y;
    const int b    = blockIdx.z / 3;
    const int part = blockIdx.z % 3;

    const size_t slab = ((size_t)(b * 8 + g)) << 16;
    const float4 qv = *(const float4*)(Q + slab + (size_t)(h * 64 + w) * 16 + s * 4);
    const unsigned short* Kb = K0 + slab + s * 4;
    const unsigned short* Vb = V0 + slab + s * 4;

    float a0 = 0.f, a1 = 0.f, a2 = 0.f, a3 = 0.f;
    const uint2 z2 = make_uint2(0u, 0u);

    if (part == 0) {
        // qrel[t] = full 16-ch dot of q with rel column t (quad-reduced)
        float qrel[7];
        const float* rel = (g < 4) ? (rel_h + (g * 16 + s * 4) * 7)
                                   : (rel_w + ((g - 4) * 16 + s * 4) * 7);
        #pragma unroll
        for (int t = 0; t < 7; ++t) {
            float pq = qv.x * rel[t] + qv.y * rel[7 + t]
                     + qv.z * rel[14 + t] + qv.w * rel[21 + t];
            qrel[t] = quadsum(pq);
        }
        float sc[49];
        float mx = -3.4e38f;
        #pragma unroll
        for (int i = 0; i < 7; ++i) {
            const int y = h + i - 3;
            uint2 kr[7];
            #pragma unroll
            for (int j = 0; j < 7; ++j) {
                const int x = w + j - 3;
                kr[j] = (y >= 0 && y < 64 && x >= 0 && x < 64)
                      ? *(const uint2*)(Kb + (size_t)(y * 64 + x) * 16) : z2;
            }
            #pragma unroll
            for (int j = 0; j < 7; ++j) {
                float d = quadsum(dot4(qv, kr[j])) + qrel[(g < 4) ? i : j];
                sc[i * 7 + j] = d;
                mx = fmaxf(mx, d);
            }
        }
        float den = 0.f;
        #pragma unroll
        for (int k = 0; k < 49; ++k) { sc[k] = __expf(sc[k] - mx); den += sc[k]; }
        const float inv = 1.f / den;
        #pragma unroll
        for (int i = 0; i < 7; ++i) {
            const int y = h + i - 3;
            uint2 vr[7];
            #pragma unroll
            for (int j = 0; j < 7; ++j) {
                const int x = w + j - 3;
                vr[j] = (y >= 0 && y < 64 && x >= 0 && x < 64)
                      ? *(const uint2*)(Vb + (size_t)(y * 64 + x) * 16) : z2;
            }
            #pragma unroll
            for (int j = 0; j < 7; ++j) {
                const float pw = sc[i * 7 + j] * inv;
                const unsigned short* u = (const unsigned short*)&vr[j];
                a0 += pw * bf2f(u[0]); a1 += pw * bf2f(u[1]);
                a2 += pw * bf2f(u[2]); a3 += pw * bf2f(u[3]);
            }
        }
    } else if (part == 1) {
        // refine row (w offsets)
        float sc[15];
        float mx = -3.4e38f;
        uint2 kr[15];
        #pragma unroll
        for (int j = 0; j < 15; ++j) {
            const int x = w + j - 7;
            kr[j] = (x >= 0 && x < 64) ? *(const uint2*)(Kb + (size_t)(h * 64 + x) * 16) : z2;
        }
        #pragma unroll
        for (int j = 0; j < 15; ++j) {
            float d = quadsum(dot4(qv, kr[j]));
            sc[j] = d; mx = fmaxf(mx, d);
        }
        float den = 0.f;
        #pragma unroll
        for (int j = 0; j < 15; ++j) { sc[j] = __expf(sc[j] - mx); den += sc[j]; }
        const float inv = 1.f / den;
        #pragma unroll
        for (int j = 0; j < 15; ++j) {
            const int x = w + j - 7;
            uint2 vv = (x >= 0 && x < 64) ? *(const uint2*)(Vb + (size_t)(h * 64 + x) * 16) : z2;
            const float pw = sc[j] * inv;
            const unsigned short* u = (const unsigned short*)&vv;
            a0 += pw * bf2f(u[0]); a1 += pw * bf2f(u[1]);
            a2 += pw * bf2f(u[2]); a3 += pw * bf2f(u[3]);
        }
    } else {
        // refine col (h offsets)
        float sc[15];
        float mx = -3.4e38f;
        uint2 kr[15];
        #pragma unroll
        for (int i = 0; i < 15; ++i) {
            const int y = h + i - 7;
            kr[i] = (y >= 0 && y < 64) ? *(const uint2*)(Kb + (size_t)(y * 64 + w) * 16) : z2;
        }
        #pragma unroll
        for (int i = 0; i < 15; ++i) {
            float d = quadsum(dot4(qv, kr[i]));
            sc[i] = d; mx = fmaxf(mx, d);
        }
        float den = 0.f;
        #pragma unroll
        for (int i = 0; i < 15; ++i) { sc[i] = __expf(sc[i] - mx); den += sc[i]; }
        const float inv = 1.f / den;
        #pragma unroll
        for (int i = 0; i < 15; ++i) {
            const int y = h + i - 7;
            uint2 vv = (y >= 0 && y < 64) ? *(const uint2*)(Vb + (size_t)(y * 64 + w) * 16) : z2;
            const float pw = sc[i] * inv;
            const unsigned short* u = (const unsigned short*)&vv;
            a0 += pw * bf2f(u[0]); a1 += pw * bf2f(u[1]);
            a2 += pw * bf2f(u[2]); a3 += pw * bf2f(u[3]);
        }
    }

    // accumulate owned channels: out[b][g*16+s*4+ci][h][w] += a_ci
    float* op = out + (((size_t)(b * 128 + g * 16 + s * 4)) << 12) + h * 64 + w;
    atomicAdd(op,                       a0);
    atomicAdd(op + ((size_t)1 << 12),   a1);
    atomicAdd(op + ((size_t)2 << 12),   a2);
    atomicAdd(op + ((size_t)3 << 12),   a3);
}

// ---------------------------------------------------------------------------
extern "C" void kernel_launch(void* const* d_in, const int* in_sizes, int n_in,
                              void* d_out, int out_size, void* d_ws, size_t ws_size,
                              hipStream_t stream) {
    (void)in_sizes; (void)n_in; (void)ws_size;
    const float* fm    = (const float*)d_in[0];
    const float* wq    = (const float*)d_in[1];
    const float* wk    = (const float*)d_in[2];
    const float* wv    = (const float*)d_in[3];
    const float* rel_h = (const float*)d_in[4];
    const float* rel_w = (const float*)d_in[5];

    float* Q = (float*)d_ws;                               // 1048576 floats
    unsigned short* K0 = (unsigned short*)(Q + 1048576);   // 1048576 shorts
    unsigned short* V0 = K0 + 1048576;                     // 1048576 shorts

    hipMemsetAsync(d_out, 0, (size_t)out_size * sizeof(float), stream);
    conv_kernel<<<dim3(128, 3, 1), dim3(256), 0, stream>>>(
        fm, wq, wk, wv, Q, K0, V0);
    attn_kernel<<<dim3(64, 8, 6), dim3(256), 0, stream>>>(
        Q, K0, V0, rel_h, rel_w, (float*)d_out);
}

// Round 8
// 140.125 us; speedup vs baseline: 1.3046x; 1.3046x over previous
//
#include <hip/hip_runtime.h>
#include <hip/hip_bf16.h>

__device__ __forceinline__ float bf2f(unsigned short u) {
    union { unsigned int i; float f; } v; v.i = ((unsigned int)u) << 16; return v.f;
}
__device__ __forceinline__ unsigned short f2bf(float f) {
    __hip_bfloat16 h = __float2bfloat16(f);
    return *reinterpret_cast<unsigned short*>(&h);
}

// ws: Q fp32 [b][g][pix][ci] (4 MB) | K bf16 (2 MB) | V bf16 (2 MB)

// ---------------------------------------------------------------------------
// conv: three 1x1 convs, fp32 in/weights, fp32 accum.
// 32-px tiles -> grid (256,3) = 768 blocks (3/CU). thread = 8 ch x 2 px.
// Q -> fp32, K/V -> bf16, layout [b][g][pix][ci].
// ---------------------------------------------------------------------------
__global__ __launch_bounds__(256) void conv_kernel(
    const float* __restrict__ fm,
    const float* __restrict__ wq, const float* __restrict__ wk,
    const float* __restrict__ wv,
    float* __restrict__ Qout,
    unsigned short* __restrict__ K0,
    unsigned short* __restrict__ V0)
{
    const int sel = blockIdx.y;
    const float* W = (sel == 0) ? wq : ((sel == 1) ? wk : wv);
    const int c0 = (sel == 0) ? 128 : 0;   // Q reads fm_t1, K/V read fm_t0

    __shared__ float w_s[64 * 132];   // [k][o]
    __shared__ float x_s[64 * 36];    // [k][px] (+pad)

    const int tid = threadIdx.x;
    const int P0  = blockIdx.x * 32;
    const int b   = P0 >> 12;
    const int hw0 = P0 & 4095;

    float acc[8][2];
    #pragma unroll
    for (int i = 0; i < 8; ++i) { acc[i][0] = 0.f; acc[i][1] = 0.f; }

    const int ocb = (tid >> 4) * 8;   // out-ch base
    const int pxb = (tid & 15) * 2;   // px base

    for (int kh = 0; kh < 128; kh += 64) {
        {   // weights transposed: w_s[k][o]
            const int o    = tid >> 1;
            const int koff = (tid & 1) * 32;
            #pragma unroll
            for (int i = 0; i < 8; ++i) {
                float4 v = *(const float4*)(W + o * 128 + kh + koff + i * 4);
                w_s[(koff + i * 4 + 0) * 132 + o] = v.x;
                w_s[(koff + i * 4 + 1) * 132 + o] = v.y;
                w_s[(koff + i * 4 + 2) * 132 + o] = v.z;
                w_s[(koff + i * 4 + 3) * 132 + o] = v.w;
            }
        }
        {   // x: x_s[k][px]
            const int c  = tid >> 2;
            const int pc = (tid & 3) * 8;
            const float* src = fm + (((size_t)(b * 256 + c0 + kh + c)) << 12) + hw0 + pc;
            *(float4*)(&x_s[c * 36 + pc])     = *(const float4*)src;
            *(float4*)(&x_s[c * 36 + pc + 4]) = *(const float4*)(src + 4);
        }
        __syncthreads();
        #pragma unroll 8
        for (int k = 0; k < 64; ++k) {
            const float* kw = &w_s[k * 132 + ocb];
            float4 wa = *(const float4*)kw;
            float4 wb = *(const float4*)(kw + 4);
            float2 xv = *(const float2*)(&x_s[k * 36 + pxb]);
            const float wf[8] = {wa.x, wa.y, wa.z, wa.w, wb.x, wb.y, wb.z, wb.w};
            #pragma unroll
            for (int i = 0; i < 8; ++i) {
                acc[i][0] += wf[i] * xv.x;
                acc[i][1] += wf[i] * xv.y;
            }
        }
        __syncthreads();
    }

    const int g   = ocb >> 4;
    const int lci = ocb & 8;
    #pragma unroll
    for (int pj = 0; pj < 2; ++pj) {
        const int hw = hw0 + pxb + pj;
        const size_t base = ((((size_t)(b * 8 + g)) << 12) + hw) * 16 + lci;
        if (sel == 0) {
            *(float4*)(Qout + base)     = make_float4(acc[0][pj], acc[1][pj], acc[2][pj], acc[3][pj]);
            *(float4*)(Qout + base + 4) = make_float4(acc[4][pj], acc[5][pj], acc[6][pj], acc[7][pj]);
        } else {
            unsigned short tmp[8];
            #pragma unroll
            for (int i = 0; i < 8; ++i) tmp[i] = f2bf(acc[i][pj]);
            unsigned short* dst = ((sel == 1) ? K0 : V0) + base;
            *(uint4*)dst = *(const uint4*)tmp;
        }
    }
}

// ---------------------------------------------------------------------------
// attn A: main 7x7 (rel bias) + row refine, LDS-staged 10-row K/V band.
// block 256 = 4 rows x 64 px; grid (16, 8, 2). Plain fp32 stores.
// OOB rows zero-filled at staging (score 0 = reference); OOB cols masked.
// ---------------------------------------------------------------------------
__global__ __launch_bounds__(256) void attnA_kernel(
    const float* __restrict__ Q,
    const unsigned short* __restrict__ K0,
    const unsigned short* __restrict__ V0,
    const float* __restrict__ rel_h,
    const float* __restrict__ rel_w,
    float* __restrict__ out)
{
    __shared__ __align__(16) unsigned short ks[10 * 64 * 16];   // 20 KB
    __shared__ __align__(16) unsigned short vs[10 * 64 * 16];   // 20 KB

    const int tid = threadIdx.x;
    const int ty  = tid >> 6;          // 0..3
    const int w   = tid & 63;
    const int h0  = blockIdx.x * 4;
    const int h   = h0 + ty;
    const int g   = blockIdx.y;
    const int b   = blockIdx.z;
    const size_t slab = ((size_t)(b * 8 + g)) << 16;

    // stage rows h0-3 .. h0+6 of K and V (contiguous per row; OOB -> zeros)
    {
        const uint4* Ksrc = (const uint4*)(K0 + slab);
        const uint4* Vsrc = (const uint4*)(V0 + slab);
        uint4* kd = (uint4*)ks;
        uint4* vd = (uint4*)vs;
        #pragma unroll
        for (int it = 0; it < 5; ++it) {
            const int idx = tid + it * 256;   // 0..1279
            const int row = idx >> 7;         // 0..9
            const int off = idx & 127;        // uint4 within row
            const int rg  = h0 - 3 + row;
            uint4 kz = make_uint4(0u,0u,0u,0u), vz = make_uint4(0u,0u,0u,0u);
            if (rg >= 0 && rg < 64) {
                kz = Ksrc[rg * 128 + off];
                vz = Vsrc[rg * 128 + off];
            }
            kd[idx] = kz;
            vd[idx] = vz;
        }
    }
    __syncthreads();

    float qr[16];
    {
        const float* qp = Q + slab + (size_t)(h * 64 + w) * 16;
        #pragma unroll
        for (int ci = 0; ci < 16; ++ci) qr[ci] = qp[ci];
    }

    float qrel[7];
    {
        const float* rel = (g < 4) ? (rel_h + g * 112) : (rel_w + (g - 4) * 112);
        #pragma unroll
        for (int t = 0; t < 7; ++t) {
            float s = 0.f;
            #pragma unroll
            for (int ci = 0; ci < 16; ++ci) s += qr[ci] * rel[ci * 7 + t];
            qrel[t] = s;
        }
    }

    float acc[16];
    #pragma unroll
    for (int ci = 0; ci < 16; ++ci) acc[ci] = 0.f;

    // ---- main 7x7 (LDS rows ty..ty+6) ----
    {
        float sc[49];
        float mx = -3.4e38f;
        #pragma unroll
        for (int i = 0; i < 7; ++i) {
            const unsigned short* krow = ks + (ty + i) * 64 * 16;
            #pragma unroll
            for (int j = 0; j < 7; ++j) {
                const int x = w + j - 3;
                const bool xin = (unsigned)x < 64u;
                const int xc = xin ? x : 0;
                const unsigned short* kp = krow + xc * 16;
                float d = 0.f;
                #pragma unroll
                for (int c = 0; c < 16; ++c) d += qr[c] * bf2f(kp[c]);
                d = xin ? d : 0.f;
                d += qrel[(g < 4) ? i : j];
                sc[i * 7 + j] = d;
                mx = fmaxf(mx, d);
            }
        }
        float den = 0.f;
        #pragma unroll
        for (int k = 0; k < 49; ++k) { sc[k] = __expf(sc[k] - mx); den += sc[k]; }
        const float inv = 1.f / den;
        #pragma unroll
        for (int i = 0; i < 7; ++i) {
            const unsigned short* vrow = vs + (ty + i) * 64 * 16;
            #pragma unroll
            for (int j = 0; j < 7; ++j) {
                const int x = w + j - 3;
                const bool xin = (unsigned)x < 64u;
                const int xc = xin ? x : 0;
                const float pw = xin ? sc[i * 7 + j] * inv : 0.f;
                const unsigned short* vp = vrow + xc * 16;
                #pragma unroll
                for (int c = 0; c < 16; ++c) acc[c] += pw * bf2f(vp[c]);
            }
        }
    }
    // ---- row refine (LDS row ty+3) ----
    {
        const unsigned short* krow = ks + (ty + 3) * 64 * 16;
        const unsigned short* vrow = vs + (ty + 3) * 64 * 16;
        float sc[15];
        float mx = -3.4e38f;
        #pragma unroll
        for (int j = 0; j < 15; ++j) {
            const int x = w + j - 7;
            const bool xin = (unsigned)x < 64u;
            const int xc = xin ? x : 0;
            const unsigned short* kp = krow + xc * 16;
            float d = 0.f;
            #pragma unroll
            for (int c = 0; c < 16; ++c) d += qr[c] * bf2f(kp[c]);
            d = xin ? d : 0.f;
            sc[j] = d;
            mx = fmaxf(mx, d);
        }
        float den = 0.f;
        #pragma unroll
        for (int j = 0; j < 15; ++j) { sc[j] = __expf(sc[j] - mx); den += sc[j]; }
        const float inv = 1.f / den;
        #pragma unroll
        for (int j = 0; j < 15; ++j) {
            const int x = w + j - 7;
            const bool xin = (unsigned)x < 64u;
            const int xc = xin ? x : 0;
            const float pw = xin ? sc[j] * inv : 0.f;
            const unsigned short* vp = vrow + xc * 16;
            #pragma unroll
            for (int c = 0; c < 16; ++c) acc[c] += pw * bf2f(vp[c]);
        }
    }

    // plain store: out[b][g*16+ci][h][w]
    float* op = out + (((size_t)(b * 128 + g * 16)) << 12) + h * 64 + w;
    #pragma unroll
    for (int ci = 0; ci < 16; ++ci) op[(size_t)ci << 12] = acc[ci];
}

// ---------------------------------------------------------------------------
// attn B: col refine, LDS-staged 4-column K/V band. block 256 = 4 cols x 64 h;
// grid (16, 8, 2). out += (runs after A in stream order).
// ---------------------------------------------------------------------------
__global__ __launch_bounds__(256) void attnB_kernel(
    const float* __restrict__ Q,
    const unsigned short* __restrict__ K0,
    const unsigned short* __restrict__ V0,
    float* __restrict__ out)
{
    __shared__ __align__(16) unsigned short ks[4 * 64 * 16];   // 8 KB
    __shared__ __align__(16) unsigned short vs[4 * 64 * 16];   // 8 KB

    const int tid = threadIdx.x;
    const int wl  = tid >> 6;          // 0..3 column within band
    const int h   = tid & 63;
    const int w0  = blockIdx.x * 4;
    const int g   = blockIdx.y;
    const int b   = blockIdx.z;
    const size_t slab = ((size_t)(b * 8 + g)) << 16;

    // stage columns w0..w0+3, all 64 rows. LDS layout [w'][h][16ch].
    {
        const uint4* Ksrc = (const uint4*)(K0 + slab);
        const uint4* Vsrc = (const uint4*)(V0 + slab);
        uint4* kd = (uint4*)ks;
        uint4* vd = (uint4*)vs;
        #pragma unroll
        for (int it = 0; it < 2; ++it) {
            const int idx  = tid + it * 256;   // 0..511
            const int hh   = idx >> 3;         // 0..63
            const int rem  = idx & 7;
            const int wp   = rem >> 1;         // 0..3
            const int half = rem & 1;
            const int gidx = (hh * 64 + w0 + wp) * 2 + half;
            const int lidx = (wp * 64 + hh) * 2 + half;
            kd[lidx] = Ksrc[gidx];
            vd[lidx] = Vsrc[gidx];
        }
    }
    __syncthreads();

    float qr[16];
    {
        const float* qp = Q + slab + (size_t)(h * 64 + w0 + wl) * 16;
        #pragma unroll
        for (int ci = 0; ci < 16; ++ci) qr[ci] = qp[ci];
    }

    const unsigned short* kcol = ks + wl * 64 * 16;
    const unsigned short* vcol = vs + wl * 64 * 16;

    float sc[15];
    float mx = -3.4e38f;
    #pragma unroll
    for (int i = 0; i < 15; ++i) {
        const int y = h + i - 7;
        const bool yin = (unsigned)y < 64u;
        const int yc = yin ? y : 0;
        const unsigned short* kp = kcol + yc * 16;
        float d = 0.f;
        #pragma unroll
        for (int c = 0; c < 16; ++c) d += qr[c] * bf2f(kp[c]);
        d = yin ? d : 0.f;
        sc[i] = d;
        mx = fmaxf(mx, d);
    }
    float den = 0.f;
    #pragma unroll
    for (int i = 0; i < 15; ++i) { sc[i] = __expf(sc[i] - mx); den += sc[i]; }
    const float inv = 1.f / den;

    float acc[16];
    #pragma unroll
    for (int ci = 0; ci < 16; ++ci) acc[ci] = 0.f;
    #pragma unroll
    for (int i = 0; i < 15; ++i) {
        const int y = h + i - 7;
        const bool yin = (unsigned)y < 64u;
        const int yc = yin ? y : 0;
        const float pw = yin ? sc[i] * inv : 0.f;
        const unsigned short* vp = vcol + yc * 16;
        #pragma unroll
        for (int c = 0; c < 16; ++c) acc[c] += pw * bf2f(vp[c]);
    }

    // accumulate onto A's result (stream-ordered, unique writer per element)
    float* op = out + (((size_t)(b * 128 + g * 16)) << 12) + h * 64 + (w0 + wl);
    #pragma unroll
    for (int ci = 0; ci < 16; ++ci) {
        float* p = op + ((size_t)ci << 12);
        *p = *p + acc[ci];
    }
}

// ---------------------------------------------------------------------------
extern "C" void kernel_launch(void* const* d_in, const int* in_sizes, int n_in,
                              void* d_out, int out_size, void* d_ws, size_t ws_size,
                              hipStream_t stream) {
    (void)in_sizes; (void)n_in; (void)out_size; (void)ws_size;
    const float* fm    = (const float*)d_in[0];
    const float* wq    = (const float*)d_in[1];
    const float* wk    = (const float*)d_in[2];
    const float* wv    = (const float*)d_in[3];
    const float* rel_h = (const float*)d_in[4];
    const float* rel_w = (const float*)d_in[5];

    float* Q = (float*)d_ws;                               // 1048576 floats
    unsigned short* K0 = (unsigned short*)(Q + 1048576);   // 1048576 shorts
    unsigned short* V0 = K0 + 1048576;                     // 1048576 shorts

    conv_kernel<<<dim3(256, 3, 1), dim3(256), 0, stream>>>(
        fm, wq, wk, wv, Q, K0, V0);
    attnA_kernel<<<dim3(16, 8, 2), dim3(256), 0, stream>>>(
        Q, K0, V0, rel_h, rel_w, (float*)d_out);
    attnB_kernel<<<dim3(16, 8, 2), dim3(256), 0, stream>>>(
        Q, K0, V0, (float*)d_out);
}